// Round 5
// baseline (747.189 us; speedup 1.0000x reference)
//
#include <hip/hip_runtime.h>
#include <hip/hip_bf16.h>

#define B_  2048
#define T_  200
#define U_  128
#define NB  8      // batch rows per block

typedef __attribute__((ext_vector_type(8))) short short8;
typedef __attribute__((ext_vector_type(4))) float f32x4;
typedef __attribute__((ext_vector_type(2))) unsigned uint2v;

static __device__ inline float sigm_pre(float sum, float bS) {
  // sigmoid(sum + b) with bS = b * -log2(e)
  float e = __builtin_amdgcn_exp2f(fmaf(sum, -1.44269504088896340736f, bS));
  return __builtin_amdgcn_rcpf(1.0f + e);
}
static __device__ inline float tanh_pre(float sum, float bS) {
  // tanh(sum + b) with bS = b * 2log2(e)
  float e = __builtin_amdgcn_exp2f(fmaf(sum, 2.88539008177792681472f, bS));
  float r = __builtin_amdgcn_rcpf(1.0f + e);
  return fmaf(-2.0f, r, 1.0f);
}
static __device__ inline unsigned pk2(float a, float b) {
  union { __hip_bfloat162 h; unsigned u; } c;
  float2 t; t.x = a; t.y = b;
  c.h = __float22bfloat162_rn(t);   // v_cvt_pk_bf16_f32, RNE
  return c.u;
}
static __device__ inline short f2bf(float f) {
  union { float f; unsigned u; } v; v.f = f;
  unsigned r = v.u + 0x7FFFu + ((v.u >> 16) & 1u);
  return (short)(r >> 16);
}
static __device__ inline short8 cvt8(const f32x4 a, const f32x4 b) {
  union { unsigned u[4]; short8 s; } c;
  c.u[0] = pk2(a[0], a[1]); c.u[1] = pk2(a[2], a[3]);
  c.u[2] = pk2(b[0], b[1]); c.u[3] = pk2(b[2], b[3]);
  return c.s;
}

// ds_read_b64_tr_b16 A-fragment loader (16-lane group reads one [4][16]-bf16 tile)
#define TRFRAG(dst, addr, O0, O1)                                              \
  {                                                                            \
    uint2v _ta, _tb;                                                           \
    asm volatile("ds_read_b64_tr_b16 %0, %1 offset:" O0 : "=v"(_ta) : "v"(addr)); \
    asm volatile("ds_read_b64_tr_b16 %0, %1 offset:" O1 : "=v"(_tb) : "v"(addr)); \
    union { struct { uint2v a, b; } p; short8 s; } _u;                         \
    _u.p.a = _ta; _u.p.b = _tb;                                                \
    dst = _u.s;                                                                \
  }
#define LGKM_WAIT()                                                            \
  asm volatile("s_waitcnt lgkmcnt(0)" ::: "memory");                           \
  __builtin_amdgcn_sched_barrier(0)

// out[m][n][k] = bf16(W_m[k][n])
__global__ void prep_weights(const float* __restrict__ Wxu, const float* __restrict__ Wxr,
                             const float* __restrict__ Wxc, const float* __restrict__ Whu,
                             const float* __restrict__ Whr, const float* __restrict__ Whc,
                             short* __restrict__ out) {
  const int m = blockIdx.x >> 7;
  const int k = blockIdx.x & 127;
  const int n = threadIdx.x;
  const float* Wp;
  switch (m) {
    case 0: Wp = Wxu; break; case 1: Wp = Wxr; break; case 2: Wp = Wxc; break;
    case 3: Wp = Whu; break; case 4: Wp = Whr; break; default: Wp = Whc; break;
  }
  out[(m * 128 + n) * 128 + k] = f2bf(Wp[k * 128 + n]);
}

// 8 waves x 16 cols, NB=8 rows/block, 256 blocks (1/CU).
// Pipelined: x-projections ax*(t+1) computed at end of phase 2(t) (h-independent),
// x A-fragments loaded per-lane DIRECTLY from global (no x LDS). Phase 1's critical
// path = tr_read(h) + 2x2-split h-MFMA chains + u/r gates.
// MFMA 16x16x32 bf16: A: lane l = A[l&15][(l>>4)*8+j]; D: lane l reg r = D[4*(l>>4)+r][l&15].
// M-rows 8..15 duplicate rows 0..7 (bounded garbage; outputs only read rows 0..7).
__global__ __launch_bounds__(512, 2) void augru_scan(
    const float* __restrict__ IS, const float* __restrict__ ATT,
    const float* __restrict__ bxu, const float* __restrict__ bhu,
    const float* __restrict__ bxr, const float* __restrict__ bhr,
    const float* __restrict__ bxc, const float* __restrict__ bhc,
    const short* __restrict__ WT, float* __restrict__ out) {
  __shared__ __align__(128) short h_T[128][16];   // h_T[hidden][row]
  __shared__ __align__(128) short rh_T[128][16];  // (r*h)_T[hidden][row]
  __shared__ __align__(16)  float att_s[T_][NB];

  const int tid  = threadIdx.x;
  const int w    = tid >> 6;
  const int l    = tid & 63;
  const int l15  = l & 15;
  const int lg   = l >> 4;
  const int b0   = blockIdx.x * NB;
  const int col  = w * 16 + l15;

  // zero h_T / rh_T (h starts at 0)
  for (int i = tid; i < 128 * 16 * 2 / 2; i += 512) {
    if (i < 1024) ((int*)h_T)[i] = 0;
    else          ((int*)rh_T)[i - 1024] = 0;
  }
  for (int i = tid; i < T_ * NB; i += 512) {
    int r = i / T_, t = i % T_;
    att_s[t][r] = ATT[(size_t)(b0 + r) * T_ + t];
  }
  // per-lane x A-fragment source: row (l15&7) [rows 8..15 duplicate 0..7], k-base lg*8
  const float* xg = IS + (size_t)(b0 + (l15 & 7)) * (T_ * U_) + lg * 8;

  // register-resident weight B-fragments Wf[m][kf]
  short8 Wf[6][4];
#pragma unroll
  for (int m = 0; m < 6; ++m)
#pragma unroll
    for (int kf = 0; kf < 4; ++kf)
      Wf[m][kf] = *(const short8*)(WT + ((m * 128 + col) * 128 + kf * 32 + lg * 8));
#pragma unroll
  for (int m = 0; m < 6; ++m)
#pragma unroll
    for (int kf = 0; kf < 4; ++kf) asm volatile("" : "+v"(Wf[m][kf]));

  // pre-scaled fused biases
  const float buS = (bxu[col] + bhu[col]) * -1.44269504088896340736f;
  const float brS = (bxr[col] + bhr[col]) * -1.44269504088896340736f;
  const float bcS = (bxc[col] + bhc[col]) * 2.88539008177792681472f;

  // loop-invariant tr-read addresses
  const unsigned trv   = (unsigned)(lg * 256 + l15 * 8);
  const unsigned adr_h = (unsigned)(size_t)(&h_T[0][0]) + trv;
  const unsigned adr_r = (unsigned)(size_t)(&rh_T[0][0]) + trv;

  const f32x4 fz = {0.0f, 0.0f, 0.0f, 0.0f};
  f32x4 hreg = fz;
  float ureg[4];

  // ---- prologue: x-projections for t=0 ----
  f32x4 axu = fz, axr = fz, axc = fz;
  {
    f32x4 xraw[8];
#pragma unroll
    for (int kf = 0; kf < 4; ++kf) {
      xraw[2 * kf]     = *(const f32x4*)(xg + kf * 32);
      xraw[2 * kf + 1] = *(const f32x4*)(xg + kf * 32 + 4);
    }
    short8 xf[4];
#pragma unroll
    for (int kf = 0; kf < 4; ++kf) xf[kf] = cvt8(xraw[2 * kf], xraw[2 * kf + 1]);
#pragma unroll
    for (int kf = 0; kf < 4; ++kf) {
      axu = __builtin_amdgcn_mfma_f32_16x16x32_bf16(xf[kf], Wf[0][kf], axu, 0, 0, 0);
      axr = __builtin_amdgcn_mfma_f32_16x16x32_bf16(xf[kf], Wf[1][kf], axr, 0, 0, 0);
      axc = __builtin_amdgcn_mfma_f32_16x16x32_bf16(xf[kf], Wf[2][kf], axc, 0, 0, 0);
    }
  }

  for (int t = 0; t < T_; ++t) {
    __syncthreads();  // h_T(t) ready
    // ---- phase 1: h-matvecs (2x2 split) + u/r gates + rh write ----
    short8 ha[4];
    TRFRAG(ha[0], adr_h, "0",    "128");
    TRFRAG(ha[1], adr_h, "1024", "1152");
    TRFRAG(ha[2], adr_h, "2048", "2176");
    TRFRAG(ha[3], adr_h, "3072", "3200");
    // issue x(t+1) loads (consumed in phase 2)
    f32x4 xraw[8];
    {
      const float* xp = xg + (size_t)(t < T_ - 1 ? t + 1 : t) * U_;
#pragma unroll
      for (int kf = 0; kf < 4; ++kf) {
        xraw[2 * kf]     = *(const f32x4*)(xp + kf * 32);
        xraw[2 * kf + 1] = *(const f32x4*)(xp + kf * 32 + 4);
      }
    }
    LGKM_WAIT();

    f32x4 ahu0 = fz, ahu1 = fz, ahr0 = fz, ahr1 = fz;
    ahu0 = __builtin_amdgcn_mfma_f32_16x16x32_bf16(ha[0], Wf[3][0], ahu0, 0, 0, 0);
    ahr0 = __builtin_amdgcn_mfma_f32_16x16x32_bf16(ha[0], Wf[4][0], ahr0, 0, 0, 0);
    ahu1 = __builtin_amdgcn_mfma_f32_16x16x32_bf16(ha[2], Wf[3][2], ahu1, 0, 0, 0);
    ahr1 = __builtin_amdgcn_mfma_f32_16x16x32_bf16(ha[2], Wf[4][2], ahr1, 0, 0, 0);
    ahu0 = __builtin_amdgcn_mfma_f32_16x16x32_bf16(ha[1], Wf[3][1], ahu0, 0, 0, 0);
    ahr0 = __builtin_amdgcn_mfma_f32_16x16x32_bf16(ha[1], Wf[4][1], ahr0, 0, 0, 0);
    ahu1 = __builtin_amdgcn_mfma_f32_16x16x32_bf16(ha[3], Wf[3][3], ahu1, 0, 0, 0);
    ahr1 = __builtin_amdgcn_mfma_f32_16x16x32_bf16(ha[3], Wf[4][3], ahr1, 0, 0, 0);

    float rh[4];
#pragma unroll
    for (int rg = 0; rg < 4; ++rg) {
      ureg[rg] = sigm_pre(axu[rg] + ahu0[rg] + ahu1[rg], buS);
      float rr = sigm_pre(axr[rg] + ahr0[rg] + ahr1[rg], brS);
      rh[rg]   = rr * hreg[rg];
    }
    {
      uint2v wv; wv[0] = pk2(rh[0], rh[1]); wv[1] = pk2(rh[2], rh[3]);
      *(uint2v*)&rh_T[col][lg * 4] = wv;
    }
    __syncthreads();  // rh_T ready
    // ---- phase 2: candidate + update, then pipelined x-projections(t+1) ----
    short8 ra[4];
    TRFRAG(ra[0], adr_r, "0",    "128");
    TRFRAG(ra[1], adr_r, "1024", "1152");
    TRFRAG(ra[2], adr_r, "2048", "2176");
    TRFRAG(ra[3], adr_r, "3072", "3200");
    const f32x4 a4 = *(const f32x4*)&att_s[t][(lg & 1) * 4];
    LGKM_WAIT();

    f32x4 ahc0 = fz, ahc1 = fz;
    ahc0 = __builtin_amdgcn_mfma_f32_16x16x32_bf16(ra[0], Wf[5][0], ahc0, 0, 0, 0);
    ahc1 = __builtin_amdgcn_mfma_f32_16x16x32_bf16(ra[2], Wf[5][2], ahc1, 0, 0, 0);
    ahc0 = __builtin_amdgcn_mfma_f32_16x16x32_bf16(ra[1], Wf[5][1], ahc0, 0, 0, 0);
    ahc1 = __builtin_amdgcn_mfma_f32_16x16x32_bf16(ra[3], Wf[5][3], ahc1, 0, 0, 0);

    float hv[4];
#pragma unroll
    for (int rg = 0; rg < 4; ++rg) {
      float cc = tanh_pre(axc[rg] + ahc0[rg] + ahc1[rg], bcS);
      float au = a4[rg] * ureg[rg];
      hv[rg] = fmaf(au, cc - hreg[rg], hreg[rg]);
      hreg[rg] = hv[rg];
    }
    {
      uint2v wv; wv[0] = pk2(hv[0], hv[1]); wv[1] = pk2(hv[2], hv[3]);
      *(uint2v*)&h_T[col][lg * 4] = wv;
    }
    // x-projections for t+1 (independent; hides under c-chain/write latency)
    {
      short8 xf[4];
#pragma unroll
      for (int kf = 0; kf < 4; ++kf) xf[kf] = cvt8(xraw[2 * kf], xraw[2 * kf + 1]);
      f32x4 nxu = fz, nxr = fz, nxc = fz;
#pragma unroll
      for (int kf = 0; kf < 4; ++kf) {
        nxu = __builtin_amdgcn_mfma_f32_16x16x32_bf16(xf[kf], Wf[0][kf], nxu, 0, 0, 0);
        nxr = __builtin_amdgcn_mfma_f32_16x16x32_bf16(xf[kf], Wf[1][kf], nxr, 0, 0, 0);
        nxc = __builtin_amdgcn_mfma_f32_16x16x32_bf16(xf[kf], Wf[2][kf], nxc, 0, 0, 0);
      }
      axu = nxu; axr = nxr; axc = nxc;
    }
  }
  // write h_final (fp32, rows 0..7 real)
#pragma unroll
  for (int rg = 0; rg < 4; ++rg) {
    const int row = lg * 4 + rg;
    if (row < NB) out[(size_t)(b0 + row) * U_ + col] = hreg[rg];
  }
}

extern "C" void kernel_launch(void* const* d_in, const int* in_sizes, int n_in,
                              void* d_out, int out_size, void* d_ws, size_t ws_size,
                              hipStream_t stream) {
  const float* IS  = (const float*)d_in[0];
  const float* ATT = (const float*)d_in[1];
  const float* Wxu = (const float*)d_in[2];  const float* bxu = (const float*)d_in[3];
  const float* Whu = (const float*)d_in[4];  const float* bhu = (const float*)d_in[5];
  const float* Wxr = (const float*)d_in[6];  const float* bxr = (const float*)d_in[7];
  const float* Whr = (const float*)d_in[8];  const float* bhr = (const float*)d_in[9];
  const float* Wxc = (const float*)d_in[10]; const float* bxc = (const float*)d_in[11];
  const float* Whc = (const float*)d_in[12]; const float* bhc = (const float*)d_in[13];
  short* WT  = (short*)d_ws;
  float* OUT = (float*)d_out;

  prep_weights<<<dim3(6 * 128), dim3(128), 0, stream>>>(Wxu, Wxr, Wxc, Whu, Whr, Whc, WT);
  augru_scan<<<dim3(B_ / NB), dim3(512), 0, stream>>>(IS, ATT, bxu, bhu, bxr, bhr, bxc, bhc, WT, OUT);
}

// Round 6
// 489.239 us; speedup vs baseline: 1.5272x; 1.5272x over previous
//
#include <hip/hip_runtime.h>
#include <hip/hip_bf16.h>

#define B_  2048
#define T_  200
#define U_  128
#define NB  8      // batch rows per block
#define PITCH 136  // x LDS pitch (bf16): 128+8 pad -> b128 reads are 2-way max

typedef __attribute__((ext_vector_type(8))) short short8;
typedef __attribute__((ext_vector_type(4))) float f32x4;
typedef __attribute__((ext_vector_type(2))) float f32x2;
typedef __attribute__((ext_vector_type(2))) unsigned uint2v;

static __device__ inline float sigm_pre(float sum, float bS) {
  // sigmoid(sum + b), bS = b * -log2(e)
  float e = __builtin_amdgcn_exp2f(fmaf(sum, -1.44269504088896340736f, bS));
  return __builtin_amdgcn_rcpf(1.0f + e);
}
static __device__ inline float tanh_pre(float sum, float bS) {
  // tanh(sum + b), bS = b * 2log2(e)
  float e = __builtin_amdgcn_exp2f(fmaf(sum, 2.88539008177792681472f, bS));
  float r = __builtin_amdgcn_rcpf(1.0f + e);
  return fmaf(-2.0f, r, 1.0f);
}
static __device__ inline unsigned pk2(float a, float b) {
  union { __hip_bfloat162 h; unsigned u; } c;
  float2 t; t.x = a; t.y = b;
  c.h = __float22bfloat162_rn(t);   // v_cvt_pk_bf16_f32
  return c.u;
}
static __device__ inline short f2bf(float f) {
  union { float f; unsigned u; } v; v.f = f;
  unsigned r = v.u + 0x7FFFu + ((v.u >> 16) & 1u);
  return (short)(r >> 16);
}

// ds_read_b64_tr_b16 A-fragment loader (16-lane group reads one [4][16]-bf16 tile)
#define TRFRAG(dst, addr, O0, O1)                                              \
  {                                                                            \
    uint2v _ta, _tb;                                                           \
    asm volatile("ds_read_b64_tr_b16 %0, %1 offset:" O0 : "=v"(_ta) : "v"(addr)); \
    asm volatile("ds_read_b64_tr_b16 %0, %1 offset:" O1 : "=v"(_tb) : "v"(addr)); \
    union { struct { uint2v a, b; } p; short8 s; } _u;                         \
    _u.p.a = _ta; _u.p.b = _tb;                                                \
    dst = _u.s;                                                                \
  }
#define LGKM_WAIT()                                                            \
  asm volatile("s_waitcnt lgkmcnt(0)" ::: "memory");                           \
  __builtin_amdgcn_sched_barrier(0)

// out[m][n][k] = bf16(W_m[k][n])
__global__ void prep_weights(const float* __restrict__ Wxu, const float* __restrict__ Wxr,
                             const float* __restrict__ Wxc, const float* __restrict__ Whu,
                             const float* __restrict__ Whr, const float* __restrict__ Whc,
                             short* __restrict__ out) {
  const int m = blockIdx.x >> 7;
  const int k = blockIdx.x & 127;
  const int n = threadIdx.x;
  const float* Wp;
  switch (m) {
    case 0: Wp = Wxu; break; case 1: Wp = Wxr; break; case 2: Wp = Wxc; break;
    case 3: Wp = Whu; break; case 4: Wp = Whr; break; default: Wp = Whc; break;
  }
  out[(m * 128 + n) * 128 + k] = f2bf(Wp[k * 128 + n]);
}

// 8 waves x 16 cols, NB=8 rows/block, 256 blocks (1/CU).
// Pipeline: x-projections for step t+1 computed at END of phase 2 of step t
// (under the tanh/h-write shadow); x is staged in double-buffered LDS with one
// coalesced f32x2 global load per lane per step (stage x(t+2) in phase 1 of t,
// read x(t+1) in phase 2 of t). h/rh transposed LDS + ds_read_b64_tr_b16.
// MFMA 16x16x32 bf16: A: lane l = A[l&15][(l>>4)*8+j]; D: lane l reg r = D[4*(l>>4)+r][l&15].
// M-rows 8..15: x rows pinned 0, h garbage bounded (convex update) -> benign.
__global__ __launch_bounds__(512, 2) void augru_scan(
    const float* __restrict__ IS, const float* __restrict__ ATT,
    const float* __restrict__ bxu, const float* __restrict__ bhu,
    const float* __restrict__ bxr, const float* __restrict__ bhr,
    const float* __restrict__ bxc, const float* __restrict__ bhc,
    const short* __restrict__ WT, float* __restrict__ out) {
  __shared__ __align__(128) short h_T[128][16];   // h_T[hidden][row]
  __shared__ __align__(128) short rh_T[128][16];  // (r*h)_T[hidden][row]
  __shared__ __align__(16)  short x0_bf[16][PITCH];
  __shared__ __align__(16)  short x1_bf[16][PITCH];
  __shared__ __align__(16)  float att_s[T_][NB];

  const int tid  = threadIdx.x;
  const int w    = tid >> 6;
  const int l    = tid & 63;
  const int l15  = l & 15;
  const int lg   = l >> 4;
  const int b0   = blockIdx.x * NB;
  const int col  = w * 16 + l15;

  // zero h_T/rh_T and both x buffers (x rows 8..15 stay zero forever)
  for (int i = tid; i < 128 * 16; i += 512) {
    ((int*)h_T)[i & 2047] = 0;  // covers h_T then rh_T via 2 passes below
  }
  for (int i = tid; i < 1024; i += 512) { ((int*)h_T)[i] = 0; }
  for (int i = tid; i < 1024; i += 512) { ((int*)rh_T)[i] = 0; }
  for (int i = tid; i < 16 * PITCH / 2; i += 512) { ((int*)x0_bf)[i] = 0; ((int*)x1_bf)[i] = 0; }
  for (int i = tid; i < T_ * NB; i += 512) {
    int r = i / T_, t = i % T_;
    att_s[t][r] = ATT[(size_t)(b0 + r) * T_ + t];
  }
  // x staging geometry: wave w stages row w, lane covers 2 consecutive k
  const int prow = w;
  const int pc2  = (tid & 63) * 2;
  const float* xptr = IS + (size_t)(b0 + prow) * (T_ * U_) + pc2;

  // register-resident weight B-fragments Wf[m][kf]
  short8 Wf[6][4];
#pragma unroll
  for (int m = 0; m < 6; ++m)
#pragma unroll
    for (int kf = 0; kf < 4; ++kf)
      Wf[m][kf] = *(const short8*)(WT + ((m * 128 + col) * 128 + kf * 32 + lg * 8));
#pragma unroll
  for (int m = 0; m < 6; ++m)
#pragma unroll
    for (int kf = 0; kf < 4; ++kf) asm volatile("" : "+v"(Wf[m][kf]));

  // pre-scaled fused biases
  const float buS = (bxu[col] + bhu[col]) * -1.44269504088896340736f;
  const float brS = (bxr[col] + bhr[col]) * -1.44269504088896340736f;
  const float bcS = (bxc[col] + bhc[col]) * 2.88539008177792681472f;

  // loop-invariant tr-read addresses
  const unsigned trv   = (unsigned)(lg * 256 + l15 * 8);
  const unsigned adr_h = (unsigned)(size_t)(&h_T[0][0]) + trv;
  const unsigned adr_r = (unsigned)(size_t)(&rh_T[0][0]) + trv;

  const f32x4 fz = {0.0f, 0.0f, 0.0f, 0.0f};
  f32x4 hreg = fz;
  float ureg[4];
  f32x4 axu = fz, axr = fz, axc = fz;   // x-projections for the CURRENT step

  // ---- prologue: stage x(0)->buf0, x(1)->buf1; compute ax*(0) from buf0 ----
  {
    f32x2 xv0 = *(const f32x2*)(xptr);
    f32x2 xv1 = *(const f32x2*)(xptr + U_);
    *(unsigned*)&x0_bf[prow][pc2] = pk2(xv0[0], xv0[1]);
    *(unsigned*)&x1_bf[prow][pc2] = pk2(xv1[0], xv1[1]);
  }
  __syncthreads();
  {
    short8 xa[4];
#pragma unroll
    for (int kf = 0; kf < 4; ++kf) xa[kf] = *(const short8*)&x0_bf[l15][kf * 32 + lg * 8];
#pragma unroll
    for (int kf = 0; kf < 4; ++kf) {
      axu = __builtin_amdgcn_mfma_f32_16x16x32_bf16(xa[kf], Wf[0][kf], axu, 0, 0, 0);
      axr = __builtin_amdgcn_mfma_f32_16x16x32_bf16(xa[kf], Wf[1][kf], axr, 0, 0, 0);
      axc = __builtin_amdgcn_mfma_f32_16x16x32_bf16(xa[kf], Wf[2][kf], axc, 0, 0, 0);
    }
  }

  // STEP(t): phase1 stages x(t+2)->xstage, phase2 reads x(t+1)<-xread and
  // computes ax*(t+1) at the end (fills the tanh/write latency shadow).
#define STEP(t, xstage, xread)                                                   \
  {                                                                              \
    __syncthreads(); /* h_T(t) ready; x(t) reads done (WAR on xstage) */         \
    short8 ha[4];                                                                \
    TRFRAG(ha[0], adr_h, "0",    "128");                                         \
    TRFRAG(ha[1], adr_h, "1024", "1152");                                        \
    TRFRAG(ha[2], adr_h, "2048", "2176");                                        \
    TRFRAG(ha[3], adr_h, "3072", "3200");                                        \
    const int ts = (t) + 2 < T_ ? (t) + 2 : T_ - 1;                              \
    f32x2 xnx = *(const f32x2*)(xptr + (size_t)ts * U_);                         \
    LGKM_WAIT();                                                                 \
    f32x4 ahu0 = fz, ahu1 = fz, ahr0 = fz, ahr1 = fz;                            \
    ahu0 = __builtin_amdgcn_mfma_f32_16x16x32_bf16(ha[0], Wf[3][0], ahu0, 0, 0, 0); \
    ahr0 = __builtin_amdgcn_mfma_f32_16x16x32_bf16(ha[0], Wf[4][0], ahr0, 0, 0, 0); \
    ahu1 = __builtin_amdgcn_mfma_f32_16x16x32_bf16(ha[2], Wf[3][2], ahu1, 0, 0, 0); \
    ahr1 = __builtin_amdgcn_mfma_f32_16x16x32_bf16(ha[2], Wf[4][2], ahr1, 0, 0, 0); \
    ahu0 = __builtin_amdgcn_mfma_f32_16x16x32_bf16(ha[1], Wf[3][1], ahu0, 0, 0, 0); \
    ahr0 = __builtin_amdgcn_mfma_f32_16x16x32_bf16(ha[1], Wf[4][1], ahr0, 0, 0, 0); \
    ahu1 = __builtin_amdgcn_mfma_f32_16x16x32_bf16(ha[3], Wf[3][3], ahu1, 0, 0, 0); \
    ahr1 = __builtin_amdgcn_mfma_f32_16x16x32_bf16(ha[3], Wf[4][3], ahr1, 0, 0, 0); \
    float rh[4];                                                                 \
    _Pragma("unroll")                                                            \
    for (int rg = 0; rg < 4; ++rg) {                                             \
      ureg[rg] = sigm_pre(axu[rg] + ahu0[rg] + ahu1[rg], buS);                   \
      float rr = sigm_pre(axr[rg] + ahr0[rg] + ahr1[rg], brS);                   \
      rh[rg]   = rr * hreg[rg];                                                  \
    }                                                                            \
    { uint2v wv; wv[0] = pk2(rh[0], rh[1]); wv[1] = pk2(rh[2], rh[3]);           \
      *(uint2v*)&rh_T[col][lg * 4] = wv; }                                       \
    *(unsigned*)&xstage[prow][pc2] = pk2(xnx[0], xnx[1]);                        \
    __syncthreads(); /* rh_T + xstage ready */                                   \
    short8 ra[4], xa[4];                                                         \
    TRFRAG(ra[0], adr_r, "0",    "128");                                         \
    TRFRAG(ra[1], adr_r, "1024", "1152");                                        \
    TRFRAG(ra[2], adr_r, "2048", "2176");                                        \
    TRFRAG(ra[3], adr_r, "3072", "3200");                                        \
    _Pragma("unroll")                                                            \
    for (int kf = 0; kf < 4; ++kf)                                               \
      xa[kf] = *(const short8*)&xread[l15][kf * 32 + lg * 8];                    \
    const f32x4 a4 = *(const f32x4*)&att_s[t][(lg & 1) * 4];                     \
    LGKM_WAIT();                                                                 \
    f32x4 ahc0 = fz, ahc1 = fz;                                                  \
    ahc0 = __builtin_amdgcn_mfma_f32_16x16x32_bf16(ra[0], Wf[5][0], ahc0, 0, 0, 0); \
    ahc1 = __builtin_amdgcn_mfma_f32_16x16x32_bf16(ra[2], Wf[5][2], ahc1, 0, 0, 0); \
    ahc0 = __builtin_amdgcn_mfma_f32_16x16x32_bf16(ra[1], Wf[5][1], ahc0, 0, 0, 0); \
    ahc1 = __builtin_amdgcn_mfma_f32_16x16x32_bf16(ra[3], Wf[5][3], ahc1, 0, 0, 0); \
    f32x4 nxu = fz, nxr = fz, nxc = fz;                                          \
    _Pragma("unroll")                                                            \
    for (int kf = 0; kf < 4; ++kf) {                                             \
      nxu = __builtin_amdgcn_mfma_f32_16x16x32_bf16(xa[kf], Wf[0][kf], nxu, 0, 0, 0); \
      nxr = __builtin_amdgcn_mfma_f32_16x16x32_bf16(xa[kf], Wf[1][kf], nxr, 0, 0, 0); \
      nxc = __builtin_amdgcn_mfma_f32_16x16x32_bf16(xa[kf], Wf[2][kf], nxc, 0, 0, 0); \
    }                                                                            \
    float hv[4];                                                                 \
    _Pragma("unroll")                                                            \
    for (int rg = 0; rg < 4; ++rg) {                                             \
      float cc = tanh_pre(axc[rg] + ahc0[rg] + ahc1[rg], bcS);                   \
      float au = a4[rg] * ureg[rg];                                              \
      hv[rg] = fmaf(au, cc - hreg[rg], hreg[rg]);                                \
      hreg[rg] = hv[rg];                                                         \
    }                                                                            \
    { uint2v wv; wv[0] = pk2(hv[0], hv[1]); wv[1] = pk2(hv[2], hv[3]);           \
      *(uint2v*)&h_T[col][lg * 4] = wv; }                                        \
    axu = nxu; axr = nxr; axc = nxc;                                             \
  }

  for (int t = 0; t < T_; t += 2) {
    STEP(t,     x0_bf, x1_bf);   // stage x(t+2)->buf0, read x(t+1)<-buf1
    STEP(t + 1, x1_bf, x0_bf);   // stage x(t+3)->buf1, read x(t+2)<-buf0
  }
#undef STEP

  // write h_final (fp32, rows 0..7 real)
#pragma unroll
  for (int rg = 0; rg < 4; ++rg) {
    const int row = lg * 4 + rg;
    if (row < NB) out[(size_t)(b0 + row) * U_ + col] = hreg[rg];
  }
}

extern "C" void kernel_launch(void* const* d_in, const int* in_sizes, int n_in,
                              void* d_out, int out_size, void* d_ws, size_t ws_size,
                              hipStream_t stream) {
  const float* IS  = (const float*)d_in[0];
  const float* ATT = (const float*)d_in[1];
  const float* Wxu = (const float*)d_in[2];  const float* bxu = (const float*)d_in[3];
  const float* Whu = (const float*)d_in[4];  const float* bhu = (const float*)d_in[5];
  const float* Wxr = (const float*)d_in[6];  const float* bxr = (const float*)d_in[7];
  const float* Whr = (const float*)d_in[8];  const float* bhr = (const float*)d_in[9];
  const float* Wxc = (const float*)d_in[10]; const float* bxc = (const float*)d_in[11];
  const float* Whc = (const float*)d_in[12]; const float* bhc = (const float*)d_in[13];
  short* WT  = (short*)d_ws;
  float* OUT = (float*)d_out;

  prep_weights<<<dim3(6 * 128), dim3(128), 0, stream>>>(Wxu, Wxr, Wxc, Whu, Whr, Whc, WT);
  augru_scan<<<dim3(B_ / NB), dim3(512), 0, stream>>>(IS, ATT, bxu, bhu, bxr, bhr, bxc, bhc, WT, OUT);
}